// Round 1
// baseline (279.423 us; speedup 1.0000x reference)
//
#include <hip/hip_runtime.h>

// Problem constants (fp32 throughout):
//   y:          (4, 64, 8, 16)            = 32768
//   pairwise_g: (4, 64, 64, 8, 8, 48)     = 50331648  (201.3 MB -> HBM-bound)
//   Wy: (32,1)  by: (1,)  Wg: (48,1)  bg: (1,)
//   out k: (4, 64, 64, 8, 8, 1)           = 1048576
//
// k[b,p1,p2,s1,s2] = dot(g[b,p1,p2,s1,s2,:], Wg) + bg + by
//                    + dot(y[b,p2,s2,:], Wy[:16])     (a-term, indexed p2,s2)
//                    + dot(y[b,p1,s1,:], Wy[16:])     (c-term, indexed p1,s1)

#define NBPS 2048            // B*P*S = 4*64*8
#define NOUT 1048576         // B*P*P*S*S

// Pre-pass: a[i] = y[i]·Wy[:16] + by + bg ; c[i] = y[i]·Wy[16:]
// ws is re-poisoned 0xAA before every timed launch -> must recompute each call.
__global__ __launch_bounds__(256) void precompute_kernel(
    const float* __restrict__ y,
    const float* __restrict__ Wy,
    const float* __restrict__ by,
    const float* __restrict__ bg,
    float* __restrict__ a,
    float* __restrict__ c) {
    int i = blockIdx.x * 256 + threadIdx.x;
    if (i >= NBPS) return;
    const float4* yv = reinterpret_cast<const float4*>(y + i * 16);
    const float4* w1 = reinterpret_cast<const float4*>(Wy);        // Wy[0:16]
    const float4* w2 = reinterpret_cast<const float4*>(Wy + 16);   // Wy[16:32]
    float sa = 0.f, sc = 0.f;
#pragma unroll
    for (int j = 0; j < 4; ++j) {
        float4 v = yv[j];
        float4 u1 = w1[j];
        float4 u2 = w2[j];
        sa += v.x * u1.x + v.y * u1.y + v.z * u1.z + v.w * u1.w;
        sc += v.x * u2.x + v.y * u2.y + v.z * u2.z + v.w * u2.w;
    }
    a[i] = sa + by[0] + bg[0];   // fold both biases into the a-term
    c[i] = sc;
}

// Main: 4 lanes per output element. Lane t of a group loads floats
// [48*o + 12*t, 48*o + 12*t + 12) of g (3 aligned float4 each; 48 B is
// 16B-aligned) and the matching slice of Wg, then a 4-lane xor-shuffle
// reduce. Per wave (16 outputs), the 3 load instructions cover 3 KB of g
// contiguously -- every byte fetched once.
__global__ __launch_bounds__(256) void main_kernel(
    const float* __restrict__ g,
    const float* __restrict__ Wg,
    const float* __restrict__ a,
    const float* __restrict__ c,
    float* __restrict__ out) {
    int tid = blockIdx.x * 256 + threadIdx.x;
    int o = tid >> 2;   // output index 0..NOUT-1
    int t = tid & 3;    // sub-lane within the 4-lane group

    const float4* gv = reinterpret_cast<const float4*>(g + (size_t)o * 48 + t * 12);
    const float4* wv = reinterpret_cast<const float4*>(Wg + t * 12);

    float s = 0.f;
#pragma unroll
    for (int j = 0; j < 3; ++j) {
        float4 v = gv[j];
        float4 w = wv[j];
        s += v.x * w.x + v.y * w.y + v.z * w.z + v.w * w.w;
    }
    // reduce across the 4-lane group (wave64: groups are lane-contiguous)
    s += __shfl_xor(s, 1);
    s += __shfl_xor(s, 2);

    if (t == 0) {
        // o = ((((b*64 + p1)*64 + p2)*8 + s1)*8 + s2)
        int s2 = o & 7;
        int s1 = (o >> 3) & 7;
        int p2 = (o >> 6) & 63;
        int p1 = (o >> 12) & 63;
        int b  = o >> 18;
        float av = a[((b << 6) + p2) * 8 + s2];
        float cv = c[((b << 6) + p1) * 8 + s1];
        out[o] = s + av + cv;
    }
}

extern "C" void kernel_launch(void* const* d_in, const int* in_sizes, int n_in,
                              void* d_out, int out_size, void* d_ws, size_t ws_size,
                              hipStream_t stream) {
    const float* y  = (const float*)d_in[0];
    const float* g  = (const float*)d_in[1];
    const float* Wy = (const float*)d_in[2];
    const float* by = (const float*)d_in[3];
    const float* Wg = (const float*)d_in[4];
    const float* bg = (const float*)d_in[5];
    float* out = (float*)d_out;

    float* a = (float*)d_ws;          // NBPS floats
    float* c = a + NBPS;              // NBPS floats (16 KB total in ws)

    precompute_kernel<<<(NBPS + 255) / 256, 256, 0, stream>>>(y, Wy, by, bg, a, c);

    // 4 threads per output -> 4*NOUT threads
    int blocks = (4 * NOUT) / 256;    // 16384
    main_kernel<<<blocks, 256, 0, stream>>>(g, Wg, a, c, out);
}